// Round 1
// baseline (6856.876 us; speedup 1.0000x reference)
//
#include <hip/hip_runtime.h>
#include <hip/hip_bf16.h>
#include <stdint.h>

#define B_ 4
#define S_ 1024
#define D_ 1024
#define H_ 16
#define F_ 4096
#define L_ 4

typedef __attribute__((ext_vector_type(8))) short short8;
typedef __attribute__((ext_vector_type(4))) short short4v;
typedef __attribute__((ext_vector_type(4))) float f32x4;

__device__ __forceinline__ short f2bf(float f) {
  unsigned u = __builtin_bit_cast(unsigned, f);
  u += 0x7fffu + ((u >> 16) & 1u);
  return (short)(u >> 16);
}

__device__ __forceinline__ void async16(const void* g, void* l) {
  __builtin_amdgcn_global_load_lds((const __attribute__((address_space(1))) void*)g,
                                   (__attribute__((address_space(3))) void*)l, 16, 0, 0);
}

// ---------------- weight transpose + fp32->bf16 convert ----------------
// wbf layout per layer l (stride 12582912 elems):
//   +0        Wq_t [1024][1024]
//   +1048576  Wk_t
//   +2097152  Wv_t
//   +3145728  Wo_t
//   +4194304  W1_t [4096][1024]
//   +8388608  W2_t [1024][4096]
__global__ __launch_bounds__(256) void wconv(
    const float* __restrict__ Wq, const float* __restrict__ Wk,
    const float* __restrict__ Wv, const float* __restrict__ Wo,
    const float* __restrict__ W1, const float* __restrict__ W2,
    short* __restrict__ wbf) {
  __shared__ float ld[32][33];
  const int bid = blockIdx.x;
  const int l = bid / 12288, r = bid % 12288;
  const float* src; short* dst; int K, N, tile;
  if (r < 4096) {
    int w = r >> 10; tile = r & 1023; K = 1024; N = 1024;
    const float* ws_ = (w == 0) ? Wq : (w == 1) ? Wk : (w == 2) ? Wv : Wo;
    src = ws_ + (size_t)l * 1048576;
    dst = wbf + (size_t)l * 12582912 + (size_t)w * 1048576;
  } else if (r < 8192) {
    tile = r - 4096; K = 1024; N = 4096;
    src = W1 + (size_t)l * 4194304;
    dst = wbf + (size_t)l * 12582912 + 4194304;
  } else {
    tile = r - 8192; K = 4096; N = 1024;
    src = W2 + (size_t)l * 4194304;
    dst = wbf + (size_t)l * 12582912 + 8388608;
  }
  const int ntn = N >> 5;
  const int tk = tile / ntn, tn = tile % ntn;
  const int t = threadIdx.x;
#pragma unroll
  for (int i = 0; i < 4; ++i) {
    int e = i * 256 + t, rr = e >> 5, c = e & 31;
    ld[rr][c] = src[(size_t)(tk * 32 + rr) * N + tn * 32 + c];
  }
  __syncthreads();
#pragma unroll
  for (int i = 0; i < 4; ++i) {
    int e = i * 256 + t, rr = e >> 5, c = e & 31;
    dst[(size_t)(tn * 32 + rr) * K + tk * 32 + c] = f2bf(ld[c][rr]);
  }
}

__global__ __launch_bounds__(256) void biaspack(
    const float* __restrict__ bq, const float* __restrict__ bk,
    const float* __restrict__ bv, float* __restrict__ out) {
  int idx = blockIdx.x * 256 + threadIdx.x;  // < L*3072
  int l = idx / 3072, j = idx % 3072;
  float v = (j < 1024) ? bq[l * 1024 + j]
          : (j < 2048) ? bk[l * 1024 + j - 1024]
                       : bv[l * 1024 + j - 2048];
  out[idx] = v;
}

// ---------------- embedding + positional encoding ----------------
__global__ __launch_bounds__(256) void embed_pe(
    const int* __restrict__ tok, const float* __restrict__ emb,
    float* __restrict__ x, short* __restrict__ xb) {
  const int row = blockIdx.x, t = threadIdx.x;
  const int s = row & (S_ - 1);
  const int d = t * 4;
  const int tk = tok[row];
  float4 e = *(const float4*)(emb + (size_t)tk * D_ + d);
  const float kpe = -0.0089944730195f;  // -ln(10000)/1024
  float a0 = s * __expf(d * kpe);
  float a1 = s * __expf((d + 2) * kpe);
  e.x += sinf(a0); e.y += cosf(a0);
  e.z += sinf(a1); e.w += cosf(a1);
  size_t off = (size_t)row * D_ + d;
  *(float4*)(x + off) = e;
  short4v v = {f2bf(e.x), f2bf(e.y), f2bf(e.z), f2bf(e.w)};
  *(short4v*)(xb + off) = v;
}

// ---------------- bf16 MFMA GEMM, B pre-transposed [N][K] ----------------
template <bool RELU, bool WBF, bool WF32>
__global__ __launch_bounds__(256) void gemm_bt(
    const short* __restrict__ A, const short* __restrict__ Wt,
    const float* __restrict__ bias, float* __restrict__ Cf,
    short* __restrict__ Cb, int N, int K) {
  __shared__ short As[128 * 32];
  __shared__ short Bs[128 * 32];
  const int tid = threadIdx.x;
  const int lane = tid & 63, w = tid >> 6;
  const int wm = w >> 1, wn = w & 1;
  const int bn = blockIdx.x, bm = blockIdx.y;

  const short* gA0 = A + (size_t)(bm * 128 + (tid >> 2)) * K + (tid & 3) * 8;
  const short* gA1 = gA0 + (size_t)64 * K;
  const short* gB0 = Wt + (size_t)(bn * 128 + (tid >> 2)) * K + (tid & 3) * 8;
  const short* gB1 = gB0 + (size_t)64 * K;
  short* lA0 = As + (w * 64) * 8;
  short* lA1 = As + (256 + w * 64) * 8;
  short* lB0 = Bs + (w * 64) * 8;
  short* lB1 = Bs + (256 + w * 64) * 8;

  f32x4 acc[4][4] = {};
  const int kgrp = (lane >> 4) * 8;
  const int rsel = lane & 15;

  for (int k0 = 0; k0 < K; k0 += 32) {
    __syncthreads();
    async16(gA0 + k0, lA0);
    async16(gA1 + k0, lA1);
    async16(gB0 + k0, lB0);
    async16(gB1 + k0, lB1);
    __syncthreads();
    short8 a[4], b[4];
#pragma unroll
    for (int f = 0; f < 4; ++f) {
      a[f] = *(const short8*)&As[(wm * 64 + f * 16 + rsel) * 32 + kgrp];
      b[f] = *(const short8*)&Bs[(wn * 64 + f * 16 + rsel) * 32 + kgrp];
    }
#pragma unroll
    for (int i = 0; i < 4; ++i)
#pragma unroll
      for (int j = 0; j < 4; ++j)
        acc[i][j] = __builtin_amdgcn_mfma_f32_16x16x32_bf16(a[i], b[j], acc[i][j], 0, 0, 0);
  }

  const int col0 = bn * 128 + wn * 64 + rsel;
  const int row0 = bm * 128 + wm * 64 + (lane >> 4) * 4;
#pragma unroll
  for (int j = 0; j < 4; ++j) {
    int col = col0 + j * 16;
    float bia = bias[col];
#pragma unroll
    for (int i = 0; i < 4; ++i) {
#pragma unroll
      for (int v = 0; v < 4; ++v) {
        int row = row0 + i * 16 + v;
        float val = acc[i][j][v] + bia;
        if constexpr (RELU) val = fmaxf(val, 0.f);
        if constexpr (WF32) Cf[(size_t)row * N + col] = val;
        if constexpr (WBF) Cb[(size_t)row * N + col] = f2bf(val);
      }
    }
  }
}

// ---------------- attention (fp32 vector, LDS-staged) ----------------
// qkv: [B*S][3072] (q|k|v), pre-biased. Writes ob bf16 [B*S][1024].
__global__ __launch_bounds__(256) void attn_kernel(
    const float* __restrict__ qkv, short* __restrict__ ob) {
  __shared__ float sc[8][1024];
  __shared__ float qs[8][64];
  __shared__ float kst[64][68];
  const int bid = blockIdx.x;
  const int qt = bid & 127;   // S/8 q-tiles
  const int bh = bid >> 7;
  const int b = bh >> 4, h = bh & 15;
  const int t = threadIdx.x;
  const int qi = t >> 5, s = t & 31;
  const size_t base = (size_t)b * S_ * 3072 + h * 64;
  const int q0 = qt * 8;

  for (int i = t; i < 8 * 64; i += 256) {
    int r = i >> 6, c = i & 63;
    qs[r][c] = qkv[base + (size_t)(q0 + r) * 3072 + c] * 0.125f;
  }
  for (int kc = 0; kc < 16; ++kc) {
    __syncthreads();
    for (int i = t; i < 64 * 64; i += 256) {
      int r = i >> 6, c = i & 63;
      kst[r][c] = qkv[base + (size_t)(kc * 64 + r) * 3072 + 1024 + c];
    }
    __syncthreads();
    float a0 = 0.f, a1 = 0.f;
    const float4* q4 = (const float4*)qs[qi];
    const float4* ka = (const float4*)kst[s];
    const float4* kb = (const float4*)kst[s + 32];
#pragma unroll
    for (int d4 = 0; d4 < 16; ++d4) {
      float4 q = q4[d4], xx = ka[d4], yy = kb[d4];
      a0 = fmaf(q.x, xx.x, fmaf(q.y, xx.y, fmaf(q.z, xx.z, fmaf(q.w, xx.w, a0))));
      a1 = fmaf(q.x, yy.x, fmaf(q.y, yy.y, fmaf(q.z, yy.z, fmaf(q.w, yy.w, a1))));
    }
    sc[qi][kc * 64 + s] = a0;
    sc[qi][kc * 64 + s + 32] = a1;
  }
  // row softmax: row qi is owned by 32 consecutive lanes of one wave
  float mx = -1e30f;
#pragma unroll 8
  for (int j = 0; j < 32; ++j) mx = fmaxf(mx, sc[qi][s + 32 * j]);
#pragma unroll
  for (int m = 16; m; m >>= 1) mx = fmaxf(mx, __shfl_xor(mx, m));
  float sum = 0.f;
#pragma unroll 8
  for (int j = 0; j < 32; ++j) {
    float p = __expf(sc[qi][s + 32 * j] - mx);
    sc[qi][s + 32 * j] = p;
    sum += p;
  }
#pragma unroll
  for (int m = 16; m; m >>= 1) sum += __shfl_xor(sum, m);
  const float inv = 1.0f / sum;

  float2 acc = {0.f, 0.f};
  const float* vb = qkv + base + 2048 + s * 2;
#pragma unroll 4
  for (int k = 0; k < 1024; ++k) {
    float p = sc[qi][k];
    float2 v = *(const float2*)(vb + (size_t)k * 3072);
    acc.x = fmaf(p, v.x, acc.x);
    acc.y = fmaf(p, v.y, acc.y);
  }
  size_t orow = (size_t)(b * S_ + q0 + qi) * 1024 + h * 64 + s * 2;
  ob[orow] = f2bf(acc.x * inv);
  ob[orow + 1] = f2bf(acc.y * inv);
}

// ---------------- residual + LayerNorm (+ bf16 recast) ----------------
__device__ __forceinline__ float blockReduce(float v, float* red) {
#pragma unroll
  for (int m = 32; m; m >>= 1) v += __shfl_xor(v, m);
  __syncthreads();
  if ((threadIdx.x & 63) == 0) red[threadIdx.x >> 6] = v;
  __syncthreads();
  return (red[0] + red[1]) + (red[2] + red[3]);
}

__global__ __launch_bounds__(256) void ln_fused(
    const float* __restrict__ xin, const float* __restrict__ res,
    const float* __restrict__ g, const float* __restrict__ be,
    float* __restrict__ xout, short* __restrict__ xbout) {
  __shared__ float red[4];
  const int row = blockIdx.x, t = threadIdx.x;
  const size_t off = (size_t)row * 1024 + t * 4;
  float4 a = *(const float4*)(xin + off);
  if (res) {
    float4 r = *(const float4*)(res + off);
    a.x += r.x; a.y += r.y; a.z += r.z; a.w += r.w;
  }
  float sum = blockReduce(a.x + a.y + a.z + a.w, red);
  float mean = sum * (1.f / 1024.f);
  float dx = a.x - mean, dy = a.y - mean, dz = a.z - mean, dw = a.w - mean;
  float ss = blockReduce(dx * dx + dy * dy + dz * dz + dw * dw, red);
  float rstd = rsqrtf(ss * (1.f / 1024.f) + 1e-5f);
  float4 gv = *(const float4*)(g + t * 4);
  float4 bv = *(const float4*)(be + t * 4);
  float4 o;
  o.x = dx * rstd * gv.x + bv.x;
  o.y = dy * rstd * gv.y + bv.y;
  o.z = dz * rstd * gv.z + bv.z;
  o.w = dw * rstd * gv.w + bv.w;
  if (xout) *(float4*)(xout + off) = o;
  if (xbout) {
    short4v ov = {f2bf(o.x), f2bf(o.y), f2bf(o.z), f2bf(o.w)};
    *(short4v*)(xbout + off) = ov;
  }
}

// ---------------- driver ----------------
extern "C" void kernel_launch(void* const* d_in, const int* in_sizes, int n_in,
                              void* d_out, int out_size, void* d_ws, size_t ws_size,
                              hipStream_t stream) {
  const int* tokens = (const int*)d_in[0];
  const float* embed = (const float*)d_in[1];
  const float* Wq = (const float*)d_in[2];
  const float* Wk = (const float*)d_in[3];
  const float* Wv = (const float*)d_in[4];
  const float* Wo = (const float*)d_in[5];
  const float* bq = (const float*)d_in[6];
  const float* bk = (const float*)d_in[7];
  const float* bv = (const float*)d_in[8];
  const float* bo = (const float*)d_in[9];
  const float* W1 = (const float*)d_in[10];
  const float* b1 = (const float*)d_in[11];
  const float* W2 = (const float*)d_in[12];
  const float* b2 = (const float*)d_in[13];
  const float* g1 = (const float*)d_in[14];
  const float* be1 = (const float*)d_in[15];
  const float* g2 = (const float*)d_in[16];
  const float* be2 = (const float*)d_in[17];
  const float* gf = (const float*)d_in[18];
  const float* bef = (const float*)d_in[19];

  char* ws = (char*)d_ws;
  short* wbf = (short*)ws;                  // 48M bf16 = 96 MB
  size_t o = 100663296;
  float* x = (float*)(ws + o);  o += 16777216;   // [4096][1024] f32
  short* xb = (short*)(ws + o); o += 8388608;    // [4096][1024] bf16
  float* qkv = (float*)(ws + o); o += 50331648;  // [4096][3072] f32
  short* obuf = (short*)(ws + o); o += 8388608;  // [4096][1024] bf16
  float* tbuf = (float*)(ws + o); o += 16777216; // [4096][1024] f32
  short* hb = (short*)(ws + o); o += 33554432;   // [4096][4096] bf16
  float* bqkv = (float*)(ws + o); o += 49152;    // [4][3072] f32
  if (ws_size < o) return;  // ws too small -> loud validation failure

  wconv<<<49152, 256, 0, stream>>>(Wq, Wk, Wv, Wo, W1, W2, wbf);
  biaspack<<<48, 256, 0, stream>>>(bq, bk, bv, bqkv);
  embed_pe<<<B_ * S_, 256, 0, stream>>>(tokens, embed, x, xb);

  for (int l = 0; l < L_; ++l) {
    const short* wl = wbf + (size_t)l * 12582912;
    // q|k|v = x @ [Wq|Wk|Wv] + b   -> qkv f32
    gemm_bt<false, false, true><<<dim3(24, 32), 256, 0, stream>>>(
        xb, wl, bqkv + l * 3072, qkv, nullptr, 3072, 1024);
    // attention -> obuf bf16
    attn_kernel<<<8192, 256, 0, stream>>>(qkv, obuf);
    // t = o @ Wo + bo
    gemm_bt<false, false, true><<<dim3(8, 32), 256, 0, stream>>>(
        obuf, wl + 3 * 1048576, bo + l * 1024, tbuf, nullptr, 1024, 1024);
    // x = LN(x + t)
    ln_fused<<<4096, 256, 0, stream>>>(x, tbuf, g1 + l * 1024, be1 + l * 1024, x, xb);
    // h = relu(x @ W1 + b1) -> bf16
    gemm_bt<true, true, false><<<dim3(32, 32), 256, 0, stream>>>(
        xb, wl + 4 * 1048576, b1 + l * 4096, nullptr, hb, 4096, 1024);
    // t = h @ W2 + b2
    gemm_bt<false, false, true><<<dim3(8, 32), 256, 0, stream>>>(
        hb, wl + 8388608, b2 + l * 1024, tbuf, nullptr, 1024, 4096);
    // x = LN(x + t)
    ln_fused<<<4096, 256, 0, stream>>>(x, tbuf, g2 + l * 1024, be2 + l * 1024, x, xb);
  }
  ln_fused<<<4096, 256, 0, stream>>>(x, nullptr, gf, bef, (float*)d_out, nullptr);
}

// Round 2
// 1715.375 us; speedup vs baseline: 3.9973x; 3.9973x over previous
//
#include <hip/hip_runtime.h>
#include <hip/hip_bf16.h>
#include <stdint.h>

#define B_ 4
#define S_ 1024
#define D_ 1024
#define H_ 16
#define F_ 4096
#define L_ 4

typedef __attribute__((ext_vector_type(8))) short short8;
typedef __attribute__((ext_vector_type(4))) short short4v;
typedef __attribute__((ext_vector_type(4))) float f32x4;

__device__ __forceinline__ short f2bf(float f) {
  unsigned u = __builtin_bit_cast(unsigned, f);
  u += 0x7fffu + ((u >> 16) & 1u);
  return (short)(u >> 16);
}

__device__ __forceinline__ void async16(const void* g, void* l) {
  __builtin_amdgcn_global_load_lds((const __attribute__((address_space(1))) void*)g,
                                   (__attribute__((address_space(3))) void*)l, 16, 0, 0);
}

// ---------------- weight transpose + fp32->bf16 convert ----------------
__global__ __launch_bounds__(256) void wconv(
    const float* __restrict__ Wq, const float* __restrict__ Wk,
    const float* __restrict__ Wv, const float* __restrict__ Wo,
    const float* __restrict__ W1, const float* __restrict__ W2,
    short* __restrict__ wbf) {
  __shared__ float ld[32][33];
  const int bid = blockIdx.x;
  const int l = bid / 12288, r = bid % 12288;
  const float* src; short* dst; int K, N, tile;
  if (r < 4096) {
    int w = r >> 10; tile = r & 1023; K = 1024; N = 1024;
    const float* ws_ = (w == 0) ? Wq : (w == 1) ? Wk : (w == 2) ? Wv : Wo;
    src = ws_ + (size_t)l * 1048576;
    dst = wbf + (size_t)l * 12582912 + (size_t)w * 1048576;
  } else if (r < 8192) {
    tile = r - 4096; K = 1024; N = 4096;
    src = W1 + (size_t)l * 4194304;
    dst = wbf + (size_t)l * 12582912 + 4194304;
  } else {
    tile = r - 8192; K = 4096; N = 1024;
    src = W2 + (size_t)l * 4194304;
    dst = wbf + (size_t)l * 12582912 + 8388608;
  }
  const int ntn = N >> 5;
  const int tk = tile / ntn, tn = tile % ntn;
  const int t = threadIdx.x;
#pragma unroll
  for (int i = 0; i < 4; ++i) {
    int e = i * 256 + t, rr = e >> 5, c = e & 31;
    ld[rr][c] = src[(size_t)(tk * 32 + rr) * N + tn * 32 + c];
  }
  __syncthreads();
#pragma unroll
  for (int i = 0; i < 4; ++i) {
    int e = i * 256 + t, rr = e >> 5, c = e & 31;
    dst[(size_t)(tn * 32 + rr) * K + tk * 32 + c] = f2bf(ld[c][rr]);
  }
}

__global__ __launch_bounds__(256) void biaspack(
    const float* __restrict__ bq, const float* __restrict__ bk,
    const float* __restrict__ bv, float* __restrict__ out) {
  int idx = blockIdx.x * 256 + threadIdx.x;
  int l = idx / 3072, j = idx % 3072;
  float v = (j < 1024) ? bq[l * 1024 + j]
          : (j < 2048) ? bk[l * 1024 + j - 1024]
                       : bv[l * 1024 + j - 2048];
  out[idx] = v;
}

// ---------------- embedding + positional encoding ----------------
__global__ __launch_bounds__(256) void embed_pe(
    const int* __restrict__ tok, const float* __restrict__ emb,
    float* __restrict__ x, short* __restrict__ xb) {
  const int row = blockIdx.x, t = threadIdx.x;
  const int s = row & (S_ - 1);
  const int d = t * 4;
  const int tk = tok[row];
  float4 e = *(const float4*)(emb + (size_t)tk * D_ + d);
  const float kpe = -0.0089944730195f;  // -ln(10000)/1024
  float a0 = s * __expf(d * kpe);
  float a1 = s * __expf((d + 2) * kpe);
  e.x += sinf(a0); e.y += cosf(a0);
  e.z += sinf(a1); e.w += cosf(a1);
  size_t off = (size_t)row * D_ + d;
  *(float4*)(x + off) = e;
  short4v v = {f2bf(e.x), f2bf(e.y), f2bf(e.z), f2bf(e.w)};
  *(short4v*)(xb + off) = v;
}

// ---------------- bf16 MFMA GEMM, B pre-transposed [N][K] ----------------
// MODE 0: f32 out; MODE 1: relu -> bf16 out; MODE 2: QKV split epilogue
template <int MODE>
__global__ __launch_bounds__(256) void gemm_bt(
    const short* __restrict__ A, const short* __restrict__ Wt,
    const float* __restrict__ bias, float* __restrict__ Cf,
    short* __restrict__ Cb, short* __restrict__ vtb, int N, int K) {
  __shared__ short As[128 * 32];
  __shared__ short Bs[128 * 32];
  const int tid = threadIdx.x;
  const int lane = tid & 63, w = tid >> 6;
  const int wm = w >> 1, wn = w & 1;
  const int bn = blockIdx.x, bm = blockIdx.y;

  const short* gA0 = A + (size_t)(bm * 128 + (tid >> 2)) * K + (tid & 3) * 8;
  const short* gA1 = gA0 + (size_t)64 * K;
  const short* gB0 = Wt + (size_t)(bn * 128 + (tid >> 2)) * K + (tid & 3) * 8;
  const short* gB1 = gB0 + (size_t)64 * K;
  short* lA0 = As + (w * 64) * 8;
  short* lA1 = As + (256 + w * 64) * 8;
  short* lB0 = Bs + (w * 64) * 8;
  short* lB1 = Bs + (256 + w * 64) * 8;

  f32x4 acc[4][4] = {};
  const int kgrp = (lane >> 4) * 8;
  const int rsel = lane & 15;

  for (int k0 = 0; k0 < K; k0 += 32) {
    __syncthreads();
    async16(gA0 + k0, lA0);
    async16(gA1 + k0, lA1);
    async16(gB0 + k0, lB0);
    async16(gB1 + k0, lB1);
    __syncthreads();
    short8 a[4], b[4];
#pragma unroll
    for (int f = 0; f < 4; ++f) {
      a[f] = *(const short8*)&As[(wm * 64 + f * 16 + rsel) * 32 + kgrp];
      b[f] = *(const short8*)&Bs[(wn * 64 + f * 16 + rsel) * 32 + kgrp];
    }
#pragma unroll
    for (int i = 0; i < 4; ++i)
#pragma unroll
      for (int j = 0; j < 4; ++j)
        acc[i][j] = __builtin_amdgcn_mfma_f32_16x16x32_bf16(a[i], b[j], acc[i][j], 0, 0, 0);
  }

  const int col0 = bn * 128 + wn * 64 + rsel;
  const int row0 = bm * 128 + wm * 64 + (lane >> 4) * 4;

  if constexpr (MODE == 2) {
    const int region = bn >> 3;  // 0:q 1:k 2:v (block cols stay in one region)
#pragma unroll
    for (int j = 0; j < 4; ++j) {
      int col = col0 + j * 16;
      float bia = bias[col];
      if (region < 2) {
        float scl = (region == 0) ? 0.125f : 1.0f;
#pragma unroll
        for (int i = 0; i < 4; ++i)
#pragma unroll
          for (int v = 0; v < 4; ++v)
            Cb[(size_t)(row0 + i * 16 + v) * 2048 + col] =
                f2bf((acc[i][j][v] + bia) * scl);
      } else {
        int hd = col - 2048, h = hd >> 6, d = hd & 63;
#pragma unroll
        for (int i = 0; i < 4; ++i) {
          int row = row0 + i * 16;
          int b = row >> 10, s0 = row & 1023;
          short4v pk = {f2bf(acc[i][j][0] + bia), f2bf(acc[i][j][1] + bia),
                        f2bf(acc[i][j][2] + bia), f2bf(acc[i][j][3] + bia)};
          *(short4v*)&vtb[((size_t)(b * 16 + h) * 64 + d) * 1024 + s0] = pk;
        }
      }
    }
  } else {
#pragma unroll
    for (int j = 0; j < 4; ++j) {
      int col = col0 + j * 16;
      float bia = bias[col];
#pragma unroll
      for (int i = 0; i < 4; ++i) {
#pragma unroll
        for (int v = 0; v < 4; ++v) {
          int row = row0 + i * 16 + v;
          float val = acc[i][j][v] + bia;
          if constexpr (MODE == 1) {
            val = fmaxf(val, 0.f);
            Cb[(size_t)row * N + col] = f2bf(val);
          } else {
            Cf[(size_t)row * N + col] = val;
          }
        }
      }
    }
  }
}

// ---------------- MFMA flash attention ----------------
// qkb: bf16 [4096][2048]  (q pre-scaled by 0.125 | k)
// vtb: bf16 [64 bh][64 d][1024 s]  (V transposed per head)
// ob : bf16 [4096][1024]
__global__ __launch_bounds__(256) void attn_mfma(
    const short* __restrict__ qkb, const short* __restrict__ vtb,
    short* __restrict__ ob) {
  __shared__ short Ks[64 * 72];
  __shared__ short Vt[64 * 72];
  __shared__ short Pl[4][32 * 72];
  const int tid = threadIdx.x;
  const int lane = tid & 63, w = tid >> 6;
  const int qt = blockIdx.x;   // 0..7
  const int bh = blockIdx.y;   // 0..63
  const int b = bh >> 4, h = bh & 15;
  const int col16 = lane & 15, g = lane >> 4;
  const int q0 = qt * 128 + w * 32;
  const size_t rowbase = (size_t)b * 1024;

  // Q A-fragments hoisted to registers (row = lane&15, k = (lane>>4)*8)
  short8 qf[2][2];
#pragma unroll
  for (int rf = 0; rf < 2; ++rf)
#pragma unroll
    for (int ks = 0; ks < 2; ++ks)
      qf[rf][ks] = *(const short8*)&qkb[(rowbase + q0 + rf * 16 + col16) * 2048 +
                                        h * 64 + ks * 32 + g * 8];

  f32x4 Oa[2][4] = {};
  float m_s[2][4], l_s[2][4];
#pragma unroll
  for (int rf = 0; rf < 2; ++rf)
#pragma unroll
    for (int v = 0; v < 4; ++v) { m_s[rf][v] = -1e30f; l_s[rf][v] = 0.f; }

  short* Pw = Pl[w];

  for (int kc = 0; kc < 16; ++kc) {
    __syncthreads();
    {
      const int u = tid & 127;
      const int r = u >> 1, half = u & 1;
      const short* src;
      short* dst;
      if (tid < 128) {
        src = qkb + (rowbase + kc * 64 + r) * 2048 + 1024 + h * 64 + half * 32;
        dst = Ks + r * 72 + half * 32;
      } else {
        src = vtb + (size_t)bh * 65536 + (size_t)r * 1024 + kc * 64 + half * 32;
        dst = Vt + r * 72 + half * 32;
      }
#pragma unroll
      for (int j = 0; j < 4; ++j)
        *(short8*)(dst + j * 8) = *(const short8*)(src + j * 8);
    }
    __syncthreads();

    // S = Q @ K^T  (per wave: [32 q][64 kv])
    f32x4 S[2][4] = {};
#pragma unroll
    for (int ks = 0; ks < 2; ++ks)
#pragma unroll
      for (int cf = 0; cf < 4; ++cf) {
        short8 kf = *(const short8*)&Ks[(cf * 16 + col16) * 72 + ks * 32 + g * 8];
#pragma unroll
        for (int rf = 0; rf < 2; ++rf)
          S[rf][cf] = __builtin_amdgcn_mfma_f32_16x16x32_bf16(qf[rf][ks], kf, S[rf][cf], 0, 0, 0);
      }

    // online softmax (C layout: col = lane&15, row = g*4 + v)
#pragma unroll
    for (int rf = 0; rf < 2; ++rf) {
      float al[4];
#pragma unroll
      for (int v = 0; v < 4; ++v) {
        float rmax = fmaxf(fmaxf(S[rf][0][v], S[rf][1][v]),
                           fmaxf(S[rf][2][v], S[rf][3][v]));
#pragma unroll
        for (int msk = 1; msk < 16; msk <<= 1) rmax = fmaxf(rmax, __shfl_xor(rmax, msk));
        float mn = fmaxf(m_s[rf][v], rmax);
        float alpha = __expf(m_s[rf][v] - mn);
        float rs = 0.f;
#pragma unroll
        for (int cf = 0; cf < 4; ++cf) {
          float p = __expf(S[rf][cf][v] - mn);
          S[rf][cf][v] = p;
          rs += p;
        }
#pragma unroll
        for (int msk = 1; msk < 16; msk <<= 1) rs += __shfl_xor(rs, msk);
        l_s[rf][v] = l_s[rf][v] * alpha + rs;
        m_s[rf][v] = mn;
        al[v] = alpha;
      }
#pragma unroll
      for (int df = 0; df < 4; ++df)
#pragma unroll
        for (int v = 0; v < 4; ++v) Oa[rf][df][v] *= al[v];
#pragma unroll
      for (int cf = 0; cf < 4; ++cf)
#pragma unroll
        for (int v = 0; v < 4; ++v)
          Pw[(rf * 16 + g * 4 + v) * 72 + cf * 16 + col16] = f2bf(S[rf][cf][v]);
    }

    // O += P @ V   (A = P from per-wave LDS, B = Vt)
#pragma unroll
    for (int ks = 0; ks < 2; ++ks) {
      short8 pa[2];
#pragma unroll
      for (int rf = 0; rf < 2; ++rf)
        pa[rf] = *(const short8*)&Pw[(rf * 16 + col16) * 72 + ks * 32 + g * 8];
#pragma unroll
      for (int df = 0; df < 4; ++df) {
        short8 vf = *(const short8*)&Vt[(df * 16 + col16) * 72 + ks * 32 + g * 8];
#pragma unroll
        for (int rf = 0; rf < 2; ++rf)
          Oa[rf][df] = __builtin_amdgcn_mfma_f32_16x16x32_bf16(pa[rf], vf, Oa[rf][df], 0, 0, 0);
      }
    }
  }

#pragma unroll
  for (int rf = 0; rf < 2; ++rf)
#pragma unroll
    for (int v = 0; v < 4; ++v) {
      float inv = 1.0f / l_s[rf][v];
      int s = q0 + rf * 16 + g * 4 + v;
#pragma unroll
      for (int df = 0; df < 4; ++df)
        ob[(rowbase + s) * 1024 + h * 64 + df * 16 + col16] =
            f2bf(Oa[rf][df][v] * inv);
    }
}

// ---------------- residual + LayerNorm (+ bf16 recast) ----------------
__device__ __forceinline__ float blockReduce(float v, float* red) {
#pragma unroll
  for (int m = 32; m; m >>= 1) v += __shfl_xor(v, m);
  __syncthreads();
  if ((threadIdx.x & 63) == 0) red[threadIdx.x >> 6] = v;
  __syncthreads();
  return (red[0] + red[1]) + (red[2] + red[3]);
}

__global__ __launch_bounds__(256) void ln_fused(
    const float* __restrict__ xin, const float* __restrict__ res,
    const float* __restrict__ g, const float* __restrict__ be,
    float* __restrict__ xout, short* __restrict__ xbout) {
  __shared__ float red[4];
  const int row = blockIdx.x, t = threadIdx.x;
  const size_t off = (size_t)row * 1024 + t * 4;
  float4 a = *(const float4*)(xin + off);
  if (res) {
    float4 r = *(const float4*)(res + off);
    a.x += r.x; a.y += r.y; a.z += r.z; a.w += r.w;
  }
  float sum = blockReduce(a.x + a.y + a.z + a.w, red);
  float mean = sum * (1.f / 1024.f);
  float dx = a.x - mean, dy = a.y - mean, dz = a.z - mean, dw = a.w - mean;
  float ss = blockReduce(dx * dx + dy * dy + dz * dz + dw * dw, red);
  float rstd = rsqrtf(ss * (1.f / 1024.f) + 1e-5f);
  float4 gv = *(const float4*)(g + t * 4);
  float4 bv = *(const float4*)(be + t * 4);
  float4 o;
  o.x = dx * rstd * gv.x + bv.x;
  o.y = dy * rstd * gv.y + bv.y;
  o.z = dz * rstd * gv.z + bv.z;
  o.w = dw * rstd * gv.w + bv.w;
  if (xout) *(float4*)(xout + off) = o;
  if (xbout) {
    short4v ov = {f2bf(o.x), f2bf(o.y), f2bf(o.z), f2bf(o.w)};
    *(short4v*)(xbout + off) = ov;
  }
}

// ---------------- driver ----------------
extern "C" void kernel_launch(void* const* d_in, const int* in_sizes, int n_in,
                              void* d_out, int out_size, void* d_ws, size_t ws_size,
                              hipStream_t stream) {
  const int* tokens = (const int*)d_in[0];
  const float* embed = (const float*)d_in[1];
  const float* Wq = (const float*)d_in[2];
  const float* Wk = (const float*)d_in[3];
  const float* Wv = (const float*)d_in[4];
  const float* Wo = (const float*)d_in[5];
  const float* bq = (const float*)d_in[6];
  const float* bk = (const float*)d_in[7];
  const float* bv = (const float*)d_in[8];
  const float* bo = (const float*)d_in[9];
  const float* W1 = (const float*)d_in[10];
  const float* b1 = (const float*)d_in[11];
  const float* W2 = (const float*)d_in[12];
  const float* b2 = (const float*)d_in[13];
  const float* g1 = (const float*)d_in[14];
  const float* be1 = (const float*)d_in[15];
  const float* g2 = (const float*)d_in[16];
  const float* be2 = (const float*)d_in[17];
  const float* gf = (const float*)d_in[18];
  const float* bef = (const float*)d_in[19];

  char* ws = (char*)d_ws;
  short* wbf = (short*)ws;                        // 96 MB
  size_t o = 100663296;
  float* x = (float*)(ws + o);  o += 16777216;    // [4096][1024] f32
  short* xb = (short*)(ws + o); o += 8388608;     // [4096][1024] bf16
  short* qkb = (short*)(ws + o); o += 16777216;   // [4096][2048] bf16 (q|k)
  short* vtb = (short*)(ws + o); o += 8388608;    // [64][64][1024] bf16 (V^T)
  short* obuf = (short*)(ws + o); o += 8388608;   // [4096][1024] bf16
  float* tbuf = (float*)(ws + o); o += 16777216;  // [4096][1024] f32
  short* hb = (short*)(ws + o); o += 33554432;    // [4096][4096] bf16
  float* bqkv = (float*)(ws + o); o += 49152;     // [4][3072] f32
  if (ws_size < o) return;

  wconv<<<49152, 256, 0, stream>>>(Wq, Wk, Wv, Wo, W1, W2, wbf);
  biaspack<<<48, 256, 0, stream>>>(bq, bk, bv, bqkv);
  embed_pe<<<B_ * S_, 256, 0, stream>>>(tokens, embed, x, xb);

  for (int l = 0; l < L_; ++l) {
    const short* wl = wbf + (size_t)l * 12582912;
    // q|k|v projection -> qkb bf16 (+scale on q), vtb bf16 transposed
    gemm_bt<2><<<dim3(24, 32), 256, 0, stream>>>(
        xb, wl, bqkv + l * 3072, nullptr, qkb, vtb, 3072, 1024);
    // flash attention -> obuf bf16
    attn_mfma<<<dim3(8, 64), 256, 0, stream>>>(qkb, vtb, obuf);
    // t = o @ Wo + bo
    gemm_bt<0><<<dim3(8, 32), 256, 0, stream>>>(
        obuf, wl + 3 * 1048576, bo + l * 1024, tbuf, nullptr, nullptr, 1024, 1024);
    // x = LN(x + t)
    ln_fused<<<4096, 256, 0, stream>>>(x, tbuf, g1 + l * 1024, be1 + l * 1024, x, xb);
    // h = relu(x @ W1 + b1) -> bf16
    gemm_bt<1><<<dim3(32, 32), 256, 0, stream>>>(
        xb, wl + 4 * 1048576, b1 + l * 4096, nullptr, hb, nullptr, 4096, 1024);
    // t = h @ W2 + b2
    gemm_bt<0><<<dim3(8, 32), 256, 0, stream>>>(
        hb, wl + 8388608, b2 + l * 1024, tbuf, nullptr, nullptr, 1024, 4096);
    // x = LN(x + t)
    ln_fused<<<4096, 256, 0, stream>>>(x, tbuf, g2 + l * 1024, be2 + l * 1024, x, xb);
  }
  ln_fused<<<4096, 256, 0, stream>>>(x, nullptr, gf, bef, (float*)d_out, nullptr);
}

// Round 4
// 1327.187 us; speedup vs baseline: 5.1665x; 1.2925x over previous
//
#include <hip/hip_runtime.h>
#include <hip/hip_bf16.h>
#include <stdint.h>

#define B_ 4
#define S_ 1024
#define D_ 1024
#define H_ 16
#define F_ 4096
#define L_ 4

typedef __attribute__((ext_vector_type(8))) short short8;
typedef __attribute__((ext_vector_type(4))) short short4v;
typedef __attribute__((ext_vector_type(4))) float f32x4;

__device__ __forceinline__ short f2bf(float f) {
  unsigned u = __builtin_bit_cast(unsigned, f);
  u += 0x7fffu + ((u >> 16) & 1u);
  return (short)(u >> 16);
}

__device__ __forceinline__ void async16(const void* g, void* l) {
  __builtin_amdgcn_global_load_lds((const __attribute__((address_space(1))) void*)g,
                                   (__attribute__((address_space(3))) void*)l, 16, 0, 0);
}

// ---------------- weight transpose + fp32->bf16 convert ----------------
__global__ __launch_bounds__(256) void wconv(
    const float* __restrict__ Wq, const float* __restrict__ Wk,
    const float* __restrict__ Wv, const float* __restrict__ Wo,
    const float* __restrict__ W1, const float* __restrict__ W2,
    short* __restrict__ wbf) {
  __shared__ float ld[32][33];
  const int bid = blockIdx.x;
  const int l = bid / 12288, r = bid % 12288;
  const float* src; short* dst; int K, N, tile;
  if (r < 4096) {
    int w = r >> 10; tile = r & 1023; K = 1024; N = 1024;
    const float* ws_ = (w == 0) ? Wq : (w == 1) ? Wk : (w == 2) ? Wv : Wo;
    src = ws_ + (size_t)l * 1048576;
    dst = wbf + (size_t)l * 12582912 + (size_t)w * 1048576;
  } else if (r < 8192) {
    tile = r - 4096; K = 1024; N = 4096;
    src = W1 + (size_t)l * 4194304;
    dst = wbf + (size_t)l * 12582912 + 4194304;
  } else {
    tile = r - 8192; K = 4096; N = 1024;
    src = W2 + (size_t)l * 4194304;
    dst = wbf + (size_t)l * 12582912 + 8388608;
  }
  const int ntn = N >> 5;
  const int tk = tile / ntn, tn = tile % ntn;
  const int t = threadIdx.x;
#pragma unroll
  for (int i = 0; i < 4; ++i) {
    int e = i * 256 + t, rr = e >> 5, c = e & 31;
    ld[rr][c] = src[(size_t)(tk * 32 + rr) * N + tn * 32 + c];
  }
  __syncthreads();
#pragma unroll
  for (int i = 0; i < 4; ++i) {
    int e = i * 256 + t, rr = e >> 5, c = e & 31;
    dst[(size_t)(tn * 32 + rr) * K + tk * 32 + c] = f2bf(ld[c][rr]);
  }
}

__global__ __launch_bounds__(256) void biaspack(
    const float* __restrict__ bq, const float* __restrict__ bk,
    const float* __restrict__ bv, float* __restrict__ out) {
  int idx = blockIdx.x * 256 + threadIdx.x;
  int l = idx / 3072, j = idx % 3072;
  float v = (j < 1024) ? bq[l * 1024 + j]
          : (j < 2048) ? bk[l * 1024 + j - 1024]
                       : bv[l * 1024 + j - 2048];
  out[idx] = v;
}

// ---------------- embedding + positional encoding ----------------
__global__ __launch_bounds__(256) void embed_pe(
    const int* __restrict__ tok, const float* __restrict__ emb,
    float* __restrict__ x, short* __restrict__ xb) {
  const int row = blockIdx.x, t = threadIdx.x;
  const int s = row & (S_ - 1);
  const int d = t * 4;
  const int tk = tok[row];
  float4 e = *(const float4*)(emb + (size_t)tk * D_ + d);
  const float kpe = -0.0089944730195f;  // -ln(10000)/1024
  float a0 = s * __expf(d * kpe);
  float a1 = s * __expf((d + 2) * kpe);
  e.x += sinf(a0); e.y += cosf(a0);
  e.z += sinf(a1); e.w += cosf(a1);
  size_t off = (size_t)row * D_ + d;
  *(float4*)(x + off) = e;
  short4v v = {f2bf(e.x), f2bf(e.y), f2bf(e.z), f2bf(e.w)};
  *(short4v*)(xb + off) = v;
}

// ============ 256x256 8-phase MFMA GEMM (T2+T3+T4+T5), B^T [N][K] ============
// EPI 1: relu->bf16 (W1); EPI 2: qkv split; EPI 3: f32 split-K partial (+bias on chunk 0)
// LDS: 2 dbuf x (A 32KB + B 32KB) = 128 KB.  Layout: [16][32]-elem subtiles,
// within-subtile swizzle: kbyte ^= (row&8)<<2 (st_16x32).  Stage = linear LDS
// dest + inverse-swizzled global source (global_load_lds is linear-dest only).
#define GBAR() __builtin_amdgcn_s_barrier()
#define WLG0() do { asm volatile("s_waitcnt lgkmcnt(0)" ::: "memory"); \
                    __builtin_amdgcn_sched_barrier(0); } while (0)

#define AF(c, m16, kh) (*(const short8*)(lds + (c) * 32768 + ((m16) * 2 + (kh)) * 512 + lo))
#define BFRD(c, n16, kh) (*(const short8*)(lds + (c) * 32768 + 16384 + ((n16) * 2 + (kh)) * 512 + lo))

#define PHASE(p, c, STGCALL, VMW) { \
    short8 a00 = AF(c, wm * 8 + (p) * 2, 0); \
    short8 a01 = AF(c, wm * 8 + (p) * 2, 1); \
    short8 a10 = AF(c, wm * 8 + (p) * 2 + 1, 0); \
    short8 a11 = AF(c, wm * 8 + (p) * 2 + 1, 1); \
    if ((p) == 0) { \
      _Pragma("unroll") for (int nf = 0; nf < 4; ++nf) { \
        Bf[nf][0] = BFRD(c, wn * 4 + nf, 0); \
        Bf[nf][1] = BFRD(c, wn * 4 + nf, 1); } } \
    STGCALL; VMW; \
    GBAR(); WLG0(); \
    __builtin_amdgcn_s_setprio(1); \
    _Pragma("unroll") for (int nf = 0; nf < 4; ++nf) { \
      acc[(p)*2][nf]   = __builtin_amdgcn_mfma_f32_16x16x32_bf16(a00, Bf[nf][0], acc[(p)*2][nf], 0, 0, 0); \
      acc[(p)*2+1][nf] = __builtin_amdgcn_mfma_f32_16x16x32_bf16(a10, Bf[nf][0], acc[(p)*2+1][nf], 0, 0, 0); } \
    _Pragma("unroll") for (int nf = 0; nf < 4; ++nf) { \
      acc[(p)*2][nf]   = __builtin_amdgcn_mfma_f32_16x16x32_bf16(a01, Bf[nf][1], acc[(p)*2][nf], 0, 0, 0); \
      acc[(p)*2+1][nf] = __builtin_amdgcn_mfma_f32_16x16x32_bf16(a11, Bf[nf][1], acc[(p)*2+1][nf], 0, 0, 0); } \
    __builtin_amdgcn_s_setprio(0); \
    GBAR(); }

template <int EPI>
__global__ __launch_bounds__(512, 2) void gemm8p(
    const short* __restrict__ A, const short* __restrict__ Bt,
    const float* __restrict__ bias, float* __restrict__ Cf,
    short* __restrict__ Cb, short* __restrict__ vtb,
    int N, int Ks, int ktiles) {
  __shared__ short lds[65536];  // 128 KB
  const int tid = threadIdx.x;
  const int lane = tid & 63, w = tid >> 6;
  const int wm = w >> 2, wn = w & 3;      // 2 x 4 waves
  const int rsel = lane & 15, g = lane >> 4;
  const int bn = blockIdx.x, bm = blockIdx.y, kcz = blockIdx.z;
  const int k0 = kcz * ktiles * 64;

  const short* gA = A + (size_t)(bm * 256) * Ks + k0;
  const short* gB = Bt + (size_t)(bn * 256) * Ks + k0;

  // staging decomposition: LDS byte o (linear) -> logical (row, kelem) with
  // inverse st_16x32 swizzle baked into the global source address
  const int o0 = tid * 16;
  const int sub0 = o0 >> 10, bb = o0 & 1023;
  const int r15 = bb >> 6, kb = bb & 63;
  const int srow = ((sub0 >> 1) << 4) + r15;
  const int ske = ((sub0 & 1) << 5) + ((kb ^ ((r15 & 8) << 2)) >> 1);

  const int lo = (rsel * 64 + ((g * 16) ^ ((rsel & 8) << 2))) >> 1;  // short units

  auto STG = [&](int t, int cbuf, int isB, int h) {
    int ts = t < ktiles ? t : ktiles - 1;
    const short* base = isB ? gB : gA;
    const short* s0 = base + (size_t)(h * 128 + srow) * Ks + ts * 64 + ske;
    char* d = (char*)lds + cbuf * 65536 + isB * 32768 + h * 16384 + tid * 16;
    async16(s0, d);
    async16(s0 + (size_t)64 * Ks, d + 8192);
  };

  f32x4 acc[8][4] = {};
  short8 Bf[4][2];

  // prologue: tile0 all 4 halves + tile1 B-halves; drain tile0 (vmcnt 4)
  STG(0, 0, 0, 0); STG(0, 0, 0, 1); STG(0, 0, 1, 0); STG(0, 0, 1, 1);
  STG(1, 1, 1, 0); STG(1, 1, 1, 1);
  asm volatile("s_waitcnt vmcnt(4)" ::: "memory");
  GBAR();

  const int niter = ktiles >> 1;
  for (int i = 0; i < niter; ++i) {
    const int t = 2 * i;
    PHASE(0, 0, STG(t + 1, 1, 0, 0), );
    PHASE(1, 0, STG(t + 1, 1, 0, 1), );
    PHASE(2, 0, STG(t + 2, 0, 1, 0), );
    PHASE(3, 0, STG(t + 2, 0, 1, 1), asm volatile("s_waitcnt vmcnt(4)" ::: "memory"));
    PHASE(0, 1, STG(t + 2, 0, 0, 0), );
    PHASE(1, 1, STG(t + 2, 0, 0, 1), );
    PHASE(2, 1, STG(t + 3, 1, 1, 0), );
    PHASE(3, 1, STG(t + 3, 1, 1, 1), asm volatile("s_waitcnt vmcnt(4)" ::: "memory"));
  }
  asm volatile("s_waitcnt vmcnt(0)" ::: "memory");

  const int colb = bn * 256 + wn * 64 + rsel;
  const int rowb = bm * 256 + wm * 128 + g * 4;

  if constexpr (EPI == 1) {
#pragma unroll
    for (int mr = 0; mr < 8; ++mr)
#pragma unroll
      for (int nf = 0; nf < 4; ++nf) {
        int col = colb + nf * 16;
        float bia = bias[col];
#pragma unroll
        for (int v = 0; v < 4; ++v) {
          int row = rowb + mr * 16 + v;
          Cb[(size_t)row * N + col] = f2bf(fmaxf(acc[mr][nf][v] + bia, 0.f));
        }
      }
  } else if constexpr (EPI == 2) {
    if (bn < 8) {
      const float scl = bn < 4 ? 0.125f : 1.0f;
#pragma unroll
      for (int mr = 0; mr < 8; ++mr)
#pragma unroll
        for (int nf = 0; nf < 4; ++nf) {
          int col = colb + nf * 16;
          float bia = bias[col];
#pragma unroll
          for (int v = 0; v < 4; ++v)
            Cb[(size_t)(rowb + mr * 16 + v) * 2048 + col] =
                f2bf((acc[mr][nf][v] + bia) * scl);
        }
    } else {
#pragma unroll
      for (int mr = 0; mr < 8; ++mr)
#pragma unroll
        for (int nf = 0; nf < 4; ++nf) {
          int col = colb + nf * 16;
          float bia = bias[col];
          int hd = col - 2048, h = hd >> 6, d = hd & 63;
          int row = rowb + mr * 16;
          int b = row >> 10, s0 = row & 1023;
          short4v pk = {f2bf(acc[mr][nf][0] + bia), f2bf(acc[mr][nf][1] + bia),
                        f2bf(acc[mr][nf][2] + bia), f2bf(acc[mr][nf][3] + bia)};
          *(short4v*)&vtb[((size_t)(b * 16 + h) * 64 + d) * 1024 + s0] = pk;
        }
    }
  } else {
    float* dst = Cf + (size_t)kcz * 4194304;
#pragma unroll
    for (int mr = 0; mr < 8; ++mr)
#pragma unroll
      for (int nf = 0; nf < 4; ++nf) {
        int col = colb + nf * 16;
        float bia = (kcz == 0) ? bias[col] : 0.f;
#pragma unroll
        for (int v = 0; v < 4; ++v)
          dst[(size_t)(rowb + mr * 16 + v) * N + col] = acc[mr][nf][v] + bia;
      }
  }
}

// ---------------- 128x128 MFMA GEMM (kept for Wo), B^T [N][K] ----------------
__global__ __launch_bounds__(256) void gemm_bt(
    const short* __restrict__ A, const short* __restrict__ Wt,
    const float* __restrict__ bias, float* __restrict__ Cf, int N, int K) {
  __shared__ short As[128 * 32];
  __shared__ short Bs[128 * 32];
  const int tid = threadIdx.x;
  const int lane = tid & 63, w = tid >> 6;
  const int wm = w >> 1, wn = w & 1;
  const int bn = blockIdx.x, bm = blockIdx.y;

  const short* gA0 = A + (size_t)(bm * 128 + (tid >> 2)) * K + (tid & 3) * 8;
  const short* gA1 = gA0 + (size_t)64 * K;
  const short* gB0 = Wt + (size_t)(bn * 128 + (tid >> 2)) * K + (tid & 3) * 8;
  const short* gB1 = gB0 + (size_t)64 * K;
  short* lA0 = As + (w * 64) * 8;
  short* lA1 = As + (256 + w * 64) * 8;
  short* lB0 = Bs + (w * 64) * 8;
  short* lB1 = Bs + (256 + w * 64) * 8;

  f32x4 acc[4][4] = {};
  const int kgrp = (lane >> 4) * 8;
  const int rsel = lane & 15;

  for (int k0 = 0; k0 < K; k0 += 32) {
    __syncthreads();
    async16(gA0 + k0, lA0);
    async16(gA1 + k0, lA1);
    async16(gB0 + k0, lB0);
    async16(gB1 + k0, lB1);
    __syncthreads();
    short8 a[4], b[4];
#pragma unroll
    for (int f = 0; f < 4; ++f) {
      a[f] = *(const short8*)&As[(wm * 64 + f * 16 + rsel) * 32 + kgrp];
      b[f] = *(const short8*)&Bs[(wn * 64 + f * 16 + rsel) * 32 + kgrp];
    }
#pragma unroll
    for (int i = 0; i < 4; ++i)
#pragma unroll
      for (int j = 0; j < 4; ++j)
        acc[i][j] = __builtin_amdgcn_mfma_f32_16x16x32_bf16(a[i], b[j], acc[i][j], 0, 0, 0);
  }

  const int col0 = bn * 128 + wn * 64 + rsel;
  const int row0 = bm * 128 + wm * 64 + (lane >> 4) * 4;
#pragma unroll
  for (int j = 0; j < 4; ++j) {
    int col = col0 + j * 16;
    float bia = bias[col];
#pragma unroll
    for (int i = 0; i < 4; ++i)
#pragma unroll
      for (int v = 0; v < 4; ++v)
        Cf[(size_t)(row0 + i * 16 + v) * N + col] = acc[i][j][v] + bia;
  }
}

// ---------------- MFMA flash attention ----------------
__global__ __launch_bounds__(256) void attn_mfma(
    const short* __restrict__ qkb, const short* __restrict__ vtb,
    short* __restrict__ ob) {
  __shared__ short Ks[64 * 72];
  __shared__ short Vt[64 * 72];
  __shared__ short Pl[4][32 * 72];
  const int tid = threadIdx.x;
  const int lane = tid & 63, w = tid >> 6;
  const int qt = blockIdx.x;
  const int bh = blockIdx.y;
  const int b = bh >> 4, h = bh & 15;
  const int col16 = lane & 15, g = lane >> 4;
  const int q0 = qt * 128 + w * 32;
  const size_t rowbase = (size_t)b * 1024;

  short8 qf[2][2];
#pragma unroll
  for (int rf = 0; rf < 2; ++rf)
#pragma unroll
    for (int ks = 0; ks < 2; ++ks)
      qf[rf][ks] = *(const short8*)&qkb[(rowbase + q0 + rf * 16 + col16) * 2048 +
                                        h * 64 + ks * 32 + g * 8];

  f32x4 Oa[2][4] = {};
  float m_s[2][4], l_s[2][4];
#pragma unroll
  for (int rf = 0; rf < 2; ++rf)
#pragma unroll
    for (int v = 0; v < 4; ++v) { m_s[rf][v] = -1e30f; l_s[rf][v] = 0.f; }

  short* Pw = Pl[w];

  for (int kc = 0; kc < 16; ++kc) {
    __syncthreads();
    {
      const int u = tid & 127;
      const int r = u >> 1, half = u & 1;
      const short* src;
      short* dst;
      if (tid < 128) {
        src = qkb + (rowbase + kc * 64 + r) * 2048 + 1024 + h * 64 + half * 32;
        dst = Ks + r * 72 + half * 32;
      } else {
        src = vtb + (size_t)bh * 65536 + (size_t)r * 1024 + kc * 64 + half * 32;
        dst = Vt + r * 72 + half * 32;
      }
#pragma unroll
      for (int j = 0; j < 4; ++j)
        *(short8*)(dst + j * 8) = *(const short8*)(src + j * 8);
    }
    __syncthreads();

    f32x4 S[2][4] = {};
#pragma unroll
    for (int ks = 0; ks < 2; ++ks)
#pragma unroll
      for (int cf = 0; cf < 4; ++cf) {
        short8 kf = *(const short8*)&Ks[(cf * 16 + col16) * 72 + ks * 32 + g * 8];
#pragma unroll
        for (int rf = 0; rf < 2; ++rf)
          S[rf][cf] = __builtin_amdgcn_mfma_f32_16x16x32_bf16(qf[rf][ks], kf, S[rf][cf], 0, 0, 0);
      }

#pragma unroll
    for (int rf = 0; rf < 2; ++rf) {
      float al[4];
#pragma unroll
      for (int v = 0; v < 4; ++v) {
        float rmax = fmaxf(fmaxf(S[rf][0][v], S[rf][1][v]),
                           fmaxf(S[rf][2][v], S[rf][3][v]));
#pragma unroll
        for (int msk = 1; msk < 16; msk <<= 1) rmax = fmaxf(rmax, __shfl_xor(rmax, msk));
        float mn = fmaxf(m_s[rf][v], rmax);
        float alpha = __expf(m_s[rf][v] - mn);
        float rs = 0.f;
#pragma unroll
        for (int cf = 0; cf < 4; ++cf) {
          float p = __expf(S[rf][cf][v] - mn);
          S[rf][cf][v] = p;
          rs += p;
        }
#pragma unroll
        for (int msk = 1; msk < 16; msk <<= 1) rs += __shfl_xor(rs, msk);
        l_s[rf][v] = l_s[rf][v] * alpha + rs;
        m_s[rf][v] = mn;
        al[v] = alpha;
      }
#pragma unroll
      for (int df = 0; df < 4; ++df)
#pragma unroll
        for (int v = 0; v < 4; ++v) Oa[rf][df][v] *= al[v];
#pragma unroll
      for (int cf = 0; cf < 4; ++cf)
#pragma unroll
        for (int v = 0; v < 4; ++v)
          Pw[(rf * 16 + g * 4 + v) * 72 + cf * 16 + col16] = f2bf(S[rf][cf][v]);
    }

#pragma unroll
    for (int ks = 0; ks < 2; ++ks) {
      short8 pa[2];
#pragma unroll
      for (int rf = 0; rf < 2; ++rf)
        pa[rf] = *(const short8*)&Pw[(rf * 16 + col16) * 72 + ks * 32 + g * 8];
#pragma unroll
      for (int df = 0; df < 4; ++df) {
        short8 vf = *(const short8*)&Vt[(df * 16 + col16) * 72 + ks * 32 + g * 8];
#pragma unroll
        for (int rf = 0; rf < 2; ++rf)
          Oa[rf][df] = __builtin_amdgcn_mfma_f32_16x16x32_bf16(pa[rf], vf, Oa[rf][df], 0, 0, 0);
      }
    }
  }

#pragma unroll
  for (int rf = 0; rf < 2; ++rf)
#pragma unroll
    for (int v = 0; v < 4; ++v) {
      float inv = 1.0f / l_s[rf][v];
      int s = q0 + rf * 16 + g * 4 + v;
#pragma unroll
      for (int df = 0; df < 4; ++df)
        ob[(rowbase + s) * 1024 + h * 64 + df * 16 + col16] =
            f2bf(Oa[rf][df][v] * inv);
    }
}

// ---------------- residual(+residual2) + LayerNorm (+ bf16 recast) ----------------
__device__ __forceinline__ float blockReduce(float v, float* red) {
#pragma unroll
  for (int m = 32; m; m >>= 1) v += __shfl_xor(v, m);
  __syncthreads();
  if ((threadIdx.x & 63) == 0) red[threadIdx.x >> 6] = v;
  __syncthreads();
  return (red[0] + red[1]) + (red[2] + red[3]);
}

__global__ __launch_bounds__(256) void ln_fused(
    const float* __restrict__ xin, const float* __restrict__ res,
    const float* __restrict__ res2,
    const float* __restrict__ g, const float* __restrict__ be,
    float* __restrict__ xout, short* __restrict__ xbout) {
  __shared__ float red[4];
  const int row = blockIdx.x, t = threadIdx.x;
  const size_t off = (size_t)row * 1024 + t * 4;
  float4 a = *(const float4*)(xin + off);
  if (res) {
    float4 r = *(const float4*)(res + off);
    a.x += r.x; a.y += r.y; a.z += r.z; a.w += r.w;
  }
  if (res2) {
    float4 r = *(const float4*)(res2 + off);
    a.x += r.x; a.y += r.y; a.z += r.z; a.w += r.w;
  }
  float sum = blockReduce(a.x + a.y + a.z + a.w, red);
  float mean = sum * (1.f / 1024.f);
  float dx = a.x - mean, dy = a.y - mean, dz = a.z - mean, dw = a.w - mean;
  float ss = blockReduce(dx * dx + dy * dy + dz * dz + dw * dw, red);
  float rstd = rsqrtf(ss * (1.f / 1024.f) + 1e-5f);
  float4 gv = *(const float4*)(g + t * 4);
  float4 bv = *(const float4*)(be + t * 4);
  float4 o;
  o.x = dx * rstd * gv.x + bv.x;
  o.y = dy * rstd * gv.y + bv.y;
  o.z = dz * rstd * gv.z + bv.z;
  o.w = dw * rstd * gv.w + bv.w;
  if (xout) *(float4*)(xout + off) = o;
  if (xbout) {
    short4v ov = {f2bf(o.x), f2bf(o.y), f2bf(o.z), f2bf(o.w)};
    *(short4v*)(xbout + off) = ov;
  }
}

// ---------------- driver ----------------
extern "C" void kernel_launch(void* const* d_in, const int* in_sizes, int n_in,
                              void* d_out, int out_size, void* d_ws, size_t ws_size,
                              hipStream_t stream) {
  const int* tokens = (const int*)d_in[0];
  const float* embed = (const float*)d_in[1];
  const float* Wq = (const float*)d_in[2];
  const float* Wk = (const float*)d_in[3];
  const float* Wv = (const float*)d_in[4];
  const float* Wo = (const float*)d_in[5];
  const float* bq = (const float*)d_in[6];
  const float* bk = (const float*)d_in[7];
  const float* bv = (const float*)d_in[8];
  const float* bo = (const float*)d_in[9];
  const float* W1 = (const float*)d_in[10];
  const float* b1 = (const float*)d_in[11];
  const float* W2 = (const float*)d_in[12];
  const float* b2 = (const float*)d_in[13];
  const float* g1 = (const float*)d_in[14];
  const float* be1 = (const float*)d_in[15];
  const float* g2 = (const float*)d_in[16];
  const float* be2 = (const float*)d_in[17];
  const float* gf = (const float*)d_in[18];
  const float* bef = (const float*)d_in[19];

  char* ws = (char*)d_ws;
  short* wbf = (short*)ws;                        // 96 MB
  size_t o = 100663296;
  float* x = (float*)(ws + o);  o += 16777216;    // [4096][1024] f32
  short* xb = (short*)(ws + o); o += 8388608;     // [4096][1024] bf16
  short* qkb = (short*)(ws + o); o += 16777216;   // [4096][2048] bf16 (q|k)
  short* vtb = (short*)(ws + o); o += 8388608;    // [64][64][1024] bf16 (V^T)
  short* obuf = (short*)(ws + o); o += 8388608;   // [4096][1024] bf16
  float* tbuf = (float*)(ws + o); o += 16777216;  // [4096][1024] f32
  short* hb = (short*)(ws + o); o += 33554432;    // [4096][4096] bf16
  float* bqkv = (float*)(ws + o); o += 49152;     // [4][3072] f32
  if (ws_size < o) return;
  // W2 split-K partials (2 x 16 MB f32) overlay qkb+vtb+obuf (dead at that point)
  float* wpart = (float*)qkb;

  wconv<<<49152, 256, 0, stream>>>(Wq, Wk, Wv, Wo, W1, W2, wbf);
  biaspack<<<48, 256, 0, stream>>>(bq, bk, bv, bqkv);
  embed_pe<<<B_ * S_, 256, 0, stream>>>(tokens, embed, x, xb);

  for (int l = 0; l < L_; ++l) {
    const short* wl = wbf + (size_t)l * 12582912;
    // q|k|v projection (256^2 8-phase) -> qkb (q scaled), vtb (V^T)
    gemm8p<2><<<dim3(12, 16), 512, 0, stream>>>(
        xb, wl, bqkv + l * 3072, nullptr, qkb, vtb, 3072, 1024, 16);
    // flash attention -> obuf bf16
    attn_mfma<<<dim3(8, 64), 256, 0, stream>>>(qkb, vtb, obuf);
    // t = o @ Wo + bo (128^2 kernel; small)
    gemm_bt<<<dim3(8, 32), 256, 0, stream>>>(
        obuf, wl + 3 * 1048576, bo + l * 1024, tbuf, 1024, 1024);
    // x = LN(x + t)
    ln_fused<<<4096, 256, 0, stream>>>(x, tbuf, nullptr,
                                       g1 + l * 1024, be1 + l * 1024, x, xb);
    // h = relu(x @ W1 + b1) -> bf16 (256^2 8-phase)
    gemm8p<1><<<dim3(16, 16), 512, 0, stream>>>(
        xb, wl + 4194304, b1 + l * 4096, nullptr, hb, nullptr, 4096, 1024, 16);
    // t = h @ W2 + b2, split-K=2 (256^2 8-phase) -> wpart[2]
    gemm8p<3><<<dim3(4, 16, 2), 512, 0, stream>>>(
        hb, wl + 8388608, b2 + l * 1024, wpart, nullptr, nullptr, 1024, 4096, 32);
    // x = LN(x + p0 + p1)
    ln_fused<<<4096, 256, 0, stream>>>(x, wpart, wpart + 4194304,
                                       g2 + l * 1024, be2 + l * 1024, x, xb);
  }
  ln_fused<<<4096, 256, 0, stream>>>(x, nullptr, nullptr, gf, bef, (float*)d_out, nullptr);
}